// Round 7
// baseline (3483.297 us; speedup 1.0000x reference)
//
#include <hip/hip_runtime.h>

typedef __attribute__((ext_vector_type(8))) short bf16x8;
typedef __attribute__((ext_vector_type(4))) float f32x4;

#define T_LEN 512
#define BATCH 128
#define HID   256
#define G4    1024
#define WPACK_STRIDE (16*4*9*64*8)   // 294912 bf16 per dir-layer

__device__ __forceinline__ float sigmf(float x){
  return __builtin_amdgcn_rcpf(1.0f + __expf(-x));
}
__device__ __forceinline__ float tanhf_(float x){
  return 1.0f - 2.0f*__builtin_amdgcn_rcpf(1.0f + __expf(2.0f*x));
}

__device__ __forceinline__ unsigned short f2bf(float f){
  union{float f;unsigned u;} v; v.f=f;
  unsigned r = v.u + 0x7FFF + ((v.u>>16)&1);
  return (unsigned short)(r>>16);
}
__device__ __forceinline__ float bf2f(unsigned short b){
  union{unsigned u;float f;} v; v.u = ((unsigned)b)<<16; return v.f;
}

// ---- pack recurrent weights into per-wave B-fragment stream order ----
// wpack[dl][w16:16][g:4][kk:9][lane:64][j:8]
// B[k][n]: n = g*256 + w16*16 + (lane&15), k = kk*32 + (lane>>4)*8 + j
__global__ void k_pack_rec(const float* __restrict__ w_hh0, const float* __restrict__ w_ih0,
                           const float* __restrict__ b0,    const float* __restrict__ w_hh1,
                           unsigned short* __restrict__ wpack){
  int idx = blockIdx.x*256 + threadIdx.x;
  if (idx >= 3*WPACK_STRIDE) return;
  int dl = idx / WPACK_STRIDE;
  int r  = idx % WPACK_STRIDE;
  int j    = r & 7;
  int lane = (r >> 3) & 63;
  int kk   = (r >> 9) % 9;
  int g    = (r / (9*512)) % 4;
  int w    = r / (4*9*512);
  int n = g*256 + w*16 + (lane & 15);
  int k = kk*32 + ((lane >> 4) << 3) + j;
  float val = 0.f;
  if (dl < 2){
    if (k < 256)       val = w_hh0[(dl*G4 + n)*HID + k];
    else if (k < 260)  val = w_ih0[(dl*G4 + n)*4 + (k - 256)];
    else if (k == 260) val = b0[dl*G4 + n];
  } else {
    if (k < 256) val = w_hh1[n*HID + k];
  }
  wpack[idx] = f2bf(val);
}

__global__ void k_pack_wih1(const float* __restrict__ w, unsigned short* __restrict__ o, int n){
  int idx = blockIdx.x*256 + threadIdx.x;
  if (idx < n) o[idx] = f2bf(w[idx]);
}

// ---- recurrence, column-split x2 with register-resident weights ----
// MODE 0: layer0 both dirs, 32 blocks. MODE 1: layer1 fwd, 16 blocks.
// Step split into own-kk phase (no partner data) and partner-kk phase; the
// tagged-payload poll sits between them, so the fabric RTT overlaps the
// own-half MFMAs + (symmetric) partner's elementwise window.
template<int MODE>
__global__ __launch_bounds__(256, 1) void k_rec(
    const float* __restrict__ x,
    const unsigned short* __restrict__ wpack,
    const unsigned short* __restrict__ xp,
    unsigned short* __restrict__ y0,
    float* __restrict__ hS,
    unsigned long long* __restrict__ hx64)    // [grp][slot:2][cb:2][16][64] u64
{
  const int tid  = threadIdx.x;
  const int lane = tid & 63;
  const int w    = tid >> 6;                  // wave 0..3
  const int bx   = blockIdx.x;
  constexpr int NGRP = (MODE == 0) ? 16 : 8;
  const int cb   = bx / NGRP;                 // column half
  const int grp  = bx % NGRP;
  int dir, bgrp;
  if (MODE == 0){ dir = grp >> 3; bgrp = grp & 7; }
  else          { dir = 0;        bgrp = grp;     }
  const int b0 = bgrp * 16;
  const int wbase16 = cb*8 + w*2;             // first of this wave's 2 w16-slices
  const int kkO = cb ? 4 : 0;                 // own-half K chunks base
  const int pkO = cb ? 0 : 4;                 // partner-half K chunks base

  __shared__ __align__(16) unsigned short A_lds[2][16*288];

  // ---- load this wave's B slice into registers, once ----
  const bf16x8* bw = (const bf16x8*)(wpack
      + ((MODE==0) ? dir*WPACK_STRIDE : 2*WPACK_STRIDE)
      + (size_t)wbase16*(4*9*512));
  constexpr int KK = (MODE == 0) ? 9 : 8;
  bf16x8 breg[2][4][KK];
  #pragma unroll
  for (int p = 0; p < 2; ++p)
    #pragma unroll
    for (int g = 0; g < 4; ++g)
      #pragma unroll
      for (int kk = 0; kk < KK; ++kk)
        breg[p][g][kk] = bw[((p*4 + g)*9 + kk)*64 + lane];

  for (int i = tid; i < 2*16*288; i += 256) ((unsigned short*)A_lds)[i] = 0;
  __syncthreads();
  if (MODE == 0 && tid < 16){
    A_lds[0][tid*288 + 260] = 0x3F80;
    A_lds[1][tid*288 + 260] = 0x3F80;
    int t0 = dir ? (T_LEN-1) : 0;
    const float* xr = &x[((size_t)(b0 + tid)*T_LEN + t0)*4];
    A_lds[0][tid*288 + 256] = f2bf(xr[0]);
    A_lds[0][tid*288 + 257] = f2bf(xr[1]);
    A_lds[0][tid*288 + 258] = f2bf(xr[2]);
    A_lds[0][tid*288 + 259] = f2bf(xr[3]);
  }

  float c_reg[2][4];
  #pragma unroll
  for (int p = 0; p < 2; ++p)
    #pragma unroll
    for (int r = 0; r < 4; ++r) c_reg[p][r] = 0.f;

  const int arow = lane & 15;
  const int rb   = (lane >> 4) * 4;
  const int odd  = lane & 1;
  int jcol[2];
  jcol[0] = wbase16*16 + (lane & 15);
  jcol[1] = jcol[0] + 16;

  // MODE1 C-in prefetch (double-buffered regs)
  uint2 cinC[2][4], cinN[2][4];
  if (MODE == 1){
    #pragma unroll
    for (int p = 0; p < 2; ++p)
      #pragma unroll
      for (int g = 0; g < 4; ++g)
        cinC[p][g] = *(const uint2*)(xp +
          ((((size_t)0*8 + bgrp)*16 + (wbase16+p))*4 + g)*256 + lane*4);
  }

  const int pcb = cb ^ 1;

  for (int tt = 0; tt < T_LEN; ++tt){
    const int t = (MODE == 0 && dir) ? (T_LEN-1-tt) : tt;
    unsigned short* Acur = (unsigned short*)A_lds[tt & 1];
    unsigned short* Anxt = (unsigned short*)A_lds[(tt + 1) & 1];

    __syncthreads();   // own-half h(tt) + x tail complete in Acur

    // ---- phase 1: own-half A fragments + MFMAs (no partner data needed) ----
    bf16x8 aO[(MODE == 0) ? 5 : 4];
    #pragma unroll
    for (int i = 0; i < 4; ++i)
      aO[i] = *(const bf16x8*)&Acur[arow*288 + (kkO+i)*32 + (lane>>4)*8];
    if (MODE == 0)
      aO[4] = *(const bf16x8*)&Acur[arow*288 + 8*32 + (lane>>4)*8];

    f32x4 acc[2][4];
    #pragma unroll
    for (int p = 0; p < 2; ++p)
      #pragma unroll
      for (int g = 0; g < 4; ++g){
        if (MODE == 1){
          uint2 cv = cinC[p][g];
          acc[p][g] = (f32x4){bf2f((unsigned short)(cv.x & 0xFFFF)),
                              bf2f((unsigned short)(cv.x >> 16)),
                              bf2f((unsigned short)(cv.y & 0xFFFF)),
                              bf2f((unsigned short)(cv.y >> 16))};
        } else {
          acc[p][g] = (f32x4){0.f, 0.f, 0.f, 0.f};
        }
      }
    if (MODE == 1){
      int tn = (t + 1 < T_LEN) ? t + 1 : t;
      #pragma unroll
      for (int p = 0; p < 2; ++p)
        #pragma unroll
        for (int g = 0; g < 4; ++g)
          cinN[p][g] = *(const uint2*)(xp +
            ((((size_t)tn*8 + bgrp)*16 + (wbase16+p))*4 + g)*256 + lane*4);
    }

    #pragma unroll
    for (int p = 0; p < 2; ++p)
      #pragma unroll
      for (int g = 0; g < 4; ++g){
        #pragma unroll
        for (int i = 0; i < 4; ++i)
          acc[p][g] = __builtin_amdgcn_mfma_f32_16x16x32_bf16(aO[i], breg[p][g][kkO+i], acc[p][g], 0, 0, 0);
        if (MODE == 0)
          acc[p][g] = __builtin_amdgcn_mfma_f32_16x16x32_bf16(aO[4], breg[p][g][8], acc[p][g], 0, 0, 0);
      }

    // ---- poll partner h(tt), write into Acur partner half as it lands ----
    if (tt > 0){
      const unsigned long long* hxp = hx64 + (size_t)(((grp*2 + ((tt-1) & 1))*2 + pcb))*1024;
      const unsigned tag = (unsigned)tt;
      unsigned remaining = 0xF;
      do {
        #pragma unroll
        for (int k = 0; k < 4; ++k){
          if (remaining & (1u << k)){
            int idx = tid + k*256;
            unsigned long long v = __hip_atomic_load(&hxp[idx],
                                     __ATOMIC_RELAXED, __HIP_MEMORY_SCOPE_AGENT);
            if ((unsigned)(v >> 32) == tag){
              *(unsigned*)&Acur[(idx >> 6)*288 + pcb*128 + (idx & 63)*2] = (unsigned)v;
              remaining &= ~(1u << k);
            }
          }
        }
      } while (remaining);
    }
    __syncthreads();   // partner half of Acur visible to all waves

    // ---- phase 2: partner-half A fragments + MFMAs ----
    bf16x8 aP[4];
    #pragma unroll
    for (int i = 0; i < 4; ++i)
      aP[i] = *(const bf16x8*)&Acur[arow*288 + (pkO+i)*32 + (lane>>4)*8];
    #pragma unroll
    for (int p = 0; p < 2; ++p)
      #pragma unroll
      for (int g = 0; g < 4; ++g)
        #pragma unroll
        for (int i = 0; i < 4; ++i)
          acc[p][g] = __builtin_amdgcn_mfma_f32_16x16x32_bf16(aP[i], breg[p][g][pkO+i], acc[p][g], 0, 0, 0);

    // ---- elementwise; fire tagged payload FIRST, then LDS/y0 writes ----
    #pragma unroll
    for (int p = 0; p < 2; ++p){
      unsigned short hbv[4];
      float hvf[4];
      #pragma unroll
      for (int r = 0; r < 4; ++r){
        float iv = acc[p][0][r], fv = acc[p][1][r], gg = acc[p][2][r], ov = acc[p][3][r];
        float c  = sigmf(fv)*c_reg[p][r] + sigmf(iv)*tanhf_(gg);
        c_reg[p][r] = c;
        float h  = sigmf(ov)*tanhf_(c);
        hvf[r] = h;
        hbv[r] = f2bf(h);
      }
      // in-register transpose to (row, col-pair) u32s via lane-pair exchange
      unsigned pk0 = (unsigned)hbv[0] | ((unsigned)hbv[1] << 16);
      unsigned pk1 = (unsigned)hbv[2] | ((unsigned)hbv[3] << 16);
      unsigned nb0 = (unsigned)__shfl_xor((int)pk0, 1, 64);
      unsigned nb1 = (unsigned)__shfl_xor((int)pk1, 1, 64);
      unsigned s0 = odd ? ((nb1 & 0xFFFFu) | (pk1 << 16))
                        : ((pk0 & 0xFFFFu) | (nb0 << 16));       // row rb + (odd?2:0)
      unsigned s1 = odd ? ((nb1 >> 16) | (pk1 & 0xFFFF0000u))
                        : ((pk0 >> 16) | (nb0 & 0xFFFF0000u));   // row rb + (odd?3:1)
      int r0 = rb + (odd ? 2 : 0);
      int cp = w*16 + p*8 + ((lane & 15) >> 1);                  // col-pair in own half
      if (tt < T_LEN-1){
        unsigned long long* hxb = hx64 + (size_t)(((grp*2 + (tt & 1))*2 + cb))*1024;
        unsigned long long tg = ((unsigned long long)(unsigned)(tt + 1)) << 32;
        __hip_atomic_store(&hxb[(r0    )*64 + cp], tg | s0,
                           __ATOMIC_RELAXED, __HIP_MEMORY_SCOPE_AGENT);
        __hip_atomic_store(&hxb[(r0 + 1)*64 + cp], tg | s1,
                           __ATOMIC_RELAXED, __HIP_MEMORY_SCOPE_AGENT);
      }
      // own h(tt+1) -> Anxt own half (shuffled u32 form)
      *(unsigned*)&Anxt[(r0    )*288 + cb*128 + cp*2] = s0;
      *(unsigned*)&Anxt[(r0 + 1)*288 + cb*128 + cp*2] = s1;
      if (MODE == 0){
        int colu = cb*128 + cp*2;
        *(unsigned*)&y0[((size_t)t*BATCH + (b0 + r0    ))*(2*HID) + dir*HID + colu] = s0;
        *(unsigned*)&y0[((size_t)t*BATCH + (b0 + r0 + 1))*(2*HID) + dir*HID + colu] = s1;
      } else if (tt == T_LEN-1){
        #pragma unroll
        for (int r = 0; r < 4; ++r)
          hS[(size_t)(b0 + rb + r)*HID + jcol[p]] = hvf[r];
      }
    }

    if (MODE == 0 && tid < 16){  // next x into Anxt tail
      int tn = dir ? (t > 0 ? t-1 : 0) : (t < T_LEN-1 ? t+1 : t);
      const float* xr = &x[((size_t)(b0 + tid)*T_LEN + tn)*4];
      Anxt[tid*288 + 256] = f2bf(xr[0]);
      Anxt[tid*288 + 257] = f2bf(xr[1]);
      Anxt[tid*288 + 258] = f2bf(xr[2]);
      Anxt[tid*288 + 259] = f2bf(xr[3]);
    }

    if (MODE == 1){
      #pragma unroll
      for (int p = 0; p < 2; ++p)
        #pragma unroll
        for (int g = 0; g < 4; ++g) cinC[p][g] = cinN[p][g];
    }
  }
}

// ---- bf16 MFMA GEMM: C[M][1024] = A[M][512] * B[1024][512]^T + bias ----
template<int PLAIN>
__global__ __launch_bounds__(256) void k_gemm_bf(
    const unsigned short* __restrict__ A, const unsigned short* __restrict__ B,
    const float* __restrict__ bias, unsigned short* __restrict__ outF, float* __restrict__ outP)
{
  __shared__ __align__(16) unsigned short As[128*64];
  __shared__ __align__(16) unsigned short Bs[128*64];
  const int tid  = threadIdx.x;
  const int lane = tid & 63;
  const int w = tid >> 6, wm = w >> 1, wn = w & 1;
  const int t  = blockIdx.y;
  const int n0 = blockIdx.x * 128;

  f32x4 acc[4][4];
  #pragma unroll
  for (int i = 0; i < 4; ++i)
    #pragma unroll
    for (int jx = 0; jx < 4; ++jx) acc[i][jx] = (f32x4){0.f,0.f,0.f,0.f};

  const int sr = tid >> 3;
  const int sq = tid & 7;

  for (int k0 = 0; k0 < 512; k0 += 64){
    #pragma unroll
    for (int it = 0; it < 4; ++it){
      int r = sr + it*32;
      uint4 av = *(const uint4*)&A[((size_t)t*128 + r)*512 + k0 + sq*8];
      uint4 bv = *(const uint4*)&B[((size_t)(n0 + r))*512 + k0 + sq*8];
      *(uint4*)&As[r*64 + (sq ^ (r & 7))*8] = av;
      *(uint4*)&Bs[r*64 + (sq ^ (r & 7))*8] = bv;
    }
    __syncthreads();
    bf16x8 af[4][2], bfv[4][2];
    #pragma unroll
    for (int mt = 0; mt < 4; ++mt)
      #pragma unroll
      for (int kk = 0; kk < 2; ++kk){
        int row = wm*64 + mt*16 + (lane & 15);
        af[mt][kk] = *(const bf16x8*)&As[row*64 + ((kk*4 + (lane>>4)) ^ (row & 7))*8];
      }
    #pragma unroll
    for (int nl = 0; nl < 4; ++nl)
      #pragma unroll
      for (int kk = 0; kk < 2; ++kk){
        int row = wn*64 + nl*16 + (lane & 15);
        bfv[nl][kk] = *(const bf16x8*)&Bs[row*64 + ((kk*4 + (lane>>4)) ^ (row & 7))*8];
      }
    #pragma unroll
    for (int mt = 0; mt < 4; ++mt)
      #pragma unroll
      for (int nl = 0; nl < 4; ++nl){
        acc[mt][nl] = __builtin_amdgcn_mfma_f32_16x16x32_bf16(af[mt][0], bfv[nl][0], acc[mt][nl], 0,0,0);
        acc[mt][nl] = __builtin_amdgcn_mfma_f32_16x16x32_bf16(af[mt][1], bfv[nl][1], acc[mt][nl], 0,0,0);
      }
    __syncthreads();
  }

  #pragma unroll
  for (int mt = 0; mt < 4; ++mt){
    #pragma unroll
    for (int nl = 0; nl < 4; ++nl){
      int ng = n0 + wn*64 + nl*16 + (lane & 15);
      float bv = bias[ng];
      f32x4 v = acc[mt][nl];
      if (PLAIN){
        int mrow = wm*64 + mt*16 + (lane >> 4)*4;
        #pragma unroll
        for (int r = 0; r < 4; ++r)
          outP[((size_t)t*128 + mrow + r)*G4 + ng] = v[r] + bv;
      } else {
        // frag-pack for k_rec<1>: [t][bgrp:8][w16:16][g:4][lane:64][r:4]
        int bgrp = wm*4 + mt;
        int wrec = (ng >> 4) & 15;
        int g    = ng >> 8;
        unsigned short hb[4];
        #pragma unroll
        for (int r = 0; r < 4; ++r) hb[r] = f2bf(v[r] + bv);
        *(uint2*)&outF[(((((size_t)t*8 + bgrp)*16 + wrec)*4 + g)*64 + lane)*4] = *(uint2*)hb;
      }
    }
  }
}

// ---- final: layer-1 bwd single step + combine + out proj + softmax ----
__global__ __launch_bounds__(256) void k_final(const float* __restrict__ hS,
                                               const float* __restrict__ xp1b,
                                               const float* __restrict__ w_out,
                                               const float* __restrict__ b_out,
                                               float* __restrict__ out)
{
  const int b = blockIdx.x, j = threadIdx.x;
  float iv = xp1b[b*G4 + 0*HID + j];
  float gv = xp1b[b*G4 + 2*HID + j];
  float ov = xp1b[b*G4 + 3*HID + j];
  float c  = sigmf(iv)*tanhf_(gv);
  float hb = sigmf(ov)*tanhf_(c);
  float last = hS[b*HID + j] + hb;

  __shared__ float part[3][256];
  part[0][j] = last * w_out[0*HID + j];
  part[1][j] = last * w_out[1*HID + j];
  part[2][j] = last * w_out[2*HID + j];
  __syncthreads();
  for (int s = 128; s > 0; s >>= 1){
    if (j < s){
      part[0][j] += part[0][j+s];
      part[1][j] += part[1][j+s];
      part[2][j] += part[2][j+s];
    }
    __syncthreads();
  }
  if (j == 0){
    float l0 = part[0][0] + b_out[0];
    float l1 = part[1][0] + b_out[1];
    float l2 = part[2][0] + b_out[2];
    float m = fmaxf(l0, fmaxf(l1, l2));
    float e0 = __expf(l0-m), e1 = __expf(l1-m), e2 = __expf(l2-m);
    float s = e0 + e1 + e2;
    out[b*3+0] = e0/s; out[b*3+1] = e1/s; out[b*3+2] = e2/s;
  }
}

extern "C" void kernel_launch(void* const* d_in, const int* in_sizes, int n_in,
                              void* d_out, int out_size, void* d_ws, size_t ws_size,
                              hipStream_t stream) {
  const float* x     = (const float*)d_in[0];
  const float* w_ih0 = (const float*)d_in[1];
  const float* w_hh0 = (const float*)d_in[2];
  const float* b0p   = (const float*)d_in[3];
  const float* w_ih1 = (const float*)d_in[4];
  const float* w_hh1 = (const float*)d_in[5];
  const float* b1p   = (const float*)d_in[6];
  const float* w_out = (const float*)d_in[7];
  const float* b_out = (const float*)d_in[8];
  float* out = (float*)d_out;

  // workspace (u16 units)
  unsigned short* y0    = (unsigned short*)d_ws;                    // 33,554,432
  unsigned short* xp1   = y0   + (size_t)T_LEN*BATCH*2*HID;         // 67,108,864
  unsigned short* wpack = xp1  + (size_t)T_LEN*BATCH*G4;            // 884,736
  unsigned short* wih1p = wpack + 3*WPACK_STRIDE;                   // 1,048,576
  float*          xp1b  = (float*)(wih1p + 2*G4*2*HID);             // 131,072 f32
  float*          hS    = xp1b + BATCH*G4;                          // 32,768 f32
  // exchange areas aliased into dead tails:
  //  MODE0: xp1 tail (xp1 written only after k_rec<0> completes): 512 KB
  //  MODE1: y0 tail (y0 dead after the gemms): 256 KB
  unsigned long long* hx0 = (unsigned long long*)(xp1 + (size_t)T_LEN*BATCH*G4 - 262144);
  unsigned long long* hx1 = (unsigned long long*)(y0 + (size_t)T_LEN*BATCH*2*HID - 131072);

  k_pack_rec<<<(3*WPACK_STRIDE + 255)/256, 256, 0, stream>>>(w_hh0, w_ih0, b0p, w_hh1, wpack);
  k_pack_wih1<<<(2*G4*2*HID + 255)/256, 256, 0, stream>>>(w_ih1, wih1p, 2*G4*2*HID);

  // layer 0, both directions, col-split x2
  hipMemsetAsync(hx0, 0, 524288, stream);
  k_rec<0><<<32, 256, 0, stream>>>(x, wpack, nullptr, y0, nullptr, hx0);

  // layer-1 input projection (fwd dir), frag-packed bf16 out
  k_gemm_bf<0><<<dim3(8, 512), 256, 0, stream>>>(y0, wih1p, b1p, xp1, nullptr);

  // layer-1 backward first step gates: plain fp32
  k_gemm_bf<1><<<dim3(8, 1), 256, 0, stream>>>(y0 + (size_t)(T_LEN-1)*BATCH*2*HID,
                                               wih1p + (size_t)G4*2*HID, b1p + G4,
                                               nullptr, xp1b);

  // layer 1 forward recurrence, col-split x2
  hipMemsetAsync(hx1, 0, 262144, stream);
  k_rec<1><<<16, 256, 0, stream>>>(nullptr, wpack, xp1, nullptr, hS, hx1);

  k_final<<<BATCH, 256, 0, stream>>>(hS, xp1b, w_out, b_out, out);
}